// Round 4
// baseline (1335.667 us; speedup 1.0000x reference)
//
#include <hip/hip_runtime.h>

// ---------------------------------------------------------------------------
// Coordinator: 8 agents, bidirectional GRU over ragged-packed sequences.
// I/O fp32. Internal compute: fp16 MFMA (fp32 accumulate), h kept fp32 in regs.
// R4: persistent k_gru (1 launch, h register/LDS-resident, XCD-pinned weights);
//     k_mlp with LayerNorm folded into weights (raw lds-direct A-stage).
// ---------------------------------------------------------------------------

typedef _Float16 f16;
typedef __attribute__((ext_vector_type(4))) _Float16 f16x4;
typedef __attribute__((ext_vector_type(8))) _Float16 f16x8;
typedef __attribute__((ext_vector_type(4))) float floatx4;

__device__ __forceinline__ float sigf(float x) { return 1.0f / (1.0f + __expf(-x)); }
__device__ __forceinline__ float tanhfast(float x) {
    float e = __expf(2.0f * x);
    return 1.0f - 2.0f / (e + 1.0f);   // saturates correctly, no NaN at +/-inf
}

// async global->LDS, 16B per lane; lds dst = wave-uniform base + lane*16
__device__ __forceinline__ void gl16(const f16* g, f16* l) {
    __builtin_amdgcn_global_load_lds((const __attribute__((address_space(1))) void*)g,
                                     (__attribute__((address_space(3))) void*)l,
                                     16, 0, 0);
}

// ---------------- empty[b] = no nonzero in comm_plans[b,:,:] -----------------
__global__ void k_empty(const float* __restrict__ comm, int* __restrict__ empty) {
    int b = blockIdx.x;
    __shared__ int flag;
    if (threadIdx.x == 0) flag = 0;
    __syncthreads();
    const float* p = comm + (size_t)b * 1024;   // 8*128
    int any = 0;
    for (int e = threadIdx.x; e < 1024; e += 256)
        if (p[e] != 0.0f) any = 1;              // -0.0 compares equal to 0
    if (any) flag = 1;
    __syncthreads();
    if (threadIdx.x == 0) empty[b] = (flag == 0);
}

// ---------------- mask[t*1024+b]: t>=8 -> 1 ; t<8 -> any(comm_sel != 0) ------
__global__ void k_mask(const float* __restrict__ plans, const float* __restrict__ comm,
                       const int* __restrict__ empty, int* __restrict__ mask) {
    int row = blockIdx.x * 4 + (threadIdx.x >> 6);   // one wave per (t,b) row
    int lane = threadIdx.x & 63;
    int t = row >> 10, b = row & 1023;
    int m;
    if (t >= 8) {
        m = 1;
    } else {
        const float* src = (empty[b] ? plans : comm) + ((size_t)b * 8 + t) * 128;
        float v0 = src[lane * 2], v1 = src[lane * 2 + 1];
        m = __any((v0 != 0.0f) || (v1 != 0.0f)) ? 1 : 0;
    }
    if (lane == 0) mask[row] = m;
}

// ---------------- single-block scan: seq_len, pack_src, scat_src, inv_scat ---
// Reproduces torch flat row-major boolean-index / masked_scatter semantics.
__global__ void k_scan(const int* __restrict__ mask, int* __restrict__ seq_len,
                       int* __restrict__ pack_src, int* __restrict__ scat_src,
                       int* __restrict__ inv_scat) {
    __shared__ int s_sl[1024];
    __shared__ int s_m[1024];
    __shared__ int s_p[1024];
    __shared__ unsigned short s_idx[16384];  // src_idx (j fits in 16 bits)
    int tid = threadIdx.x;
    int sl = 8;
    for (int t = 0; t < 8; t++) sl += mask[t * 1024 + tid];
    s_sl[tid] = sl;
    seq_len[tid] = sl;
    __syncthreads();
    int mv[16], pv[16];
    int mc = 0, pc = 0;
    int j0 = tid * 16;
    for (int q = 0; q < 16; q++) {
        int j = j0 + q;
        mv[q] = mask[j];
        pv[q] = ((j >> 10) < s_sl[j & 1023]) ? 1 : 0;
        mc += mv[q]; pc += pv[q];
    }
    s_m[tid] = mc; s_p[tid] = pc;
    __syncthreads();
    for (int off = 1; off < 1024; off <<= 1) {   // Hillis-Steele inclusive scan
        int am = (tid >= off) ? s_m[tid - off] : 0;
        int ap = (tid >= off) ? s_p[tid - off] : 0;
        __syncthreads();
        s_m[tid] += am; s_p[tid] += ap;
        __syncthreads();
    }
    if (tid == 1023) seq_len[1024] = s_m[1023];  // T = total masked count
    int moff = s_m[tid] - mc;    // exclusive prefixes
    int poff = s_p[tid] - pc;
    int rm = moff;
    for (int q = 0; q < 16; q++)
        if (mv[q]) s_idx[rm++] = (unsigned short)(j0 + q);
    __syncthreads();
    rm = moff;
    int rp = poff;
    for (int q = 0; q < 16; q++) {
        int j = j0 + q;
        scat_src[j] = mv[q] ? rm : -1;
        if (mv[q]) { inv_scat[rm] = j; rm++; }
        pack_src[j] = pv[q] ? (int)s_idx[rp] : -1;
        if (pv[q]) rp++;
    }
}

// ---------------- gather packed sequences: cseq[i][t][b][c] (fp16) -----------
__global__ void k_pack(const float* __restrict__ plans, const float* __restrict__ comm,
                       const float* __restrict__ dummy, const int* __restrict__ empty,
                       const int* __restrict__ pack_src, f16* __restrict__ cseq) {
    int row = blockIdx.x * 8 + (threadIdx.x >> 5);   // i*16384 + j
    int lane = threadIdx.x & 31;
    int i = row >> 14;
    int j = row & 16383;
    int s = pack_src[j];
    f16x8 o = {0, 0, 0, 0, 0, 0, 0, 0};
    if (s >= 0) {
        int tp = s >> 10, bp = s & 1023;
        const float* src;
        if (tp < 8) {
            if (lane < 16) src = plans + ((size_t)bp * 8 + i) * 128 + lane * 8;
            else src = (empty[bp] ? plans : comm) + ((size_t)bp * 8 + tp) * 128 + (lane - 16) * 8;
        } else {
            src = dummy + (((size_t)i * 8 + (tp - 8)) * 1024 + bp) * 256 + lane * 8;
        }
        float4 v0 = *(const float4*)src;
        float4 v1 = *(const float4*)(src + 4);
        o[0] = (f16)v0.x; o[1] = (f16)v0.y; o[2] = (f16)v0.z; o[3] = (f16)v0.w;
        o[4] = (f16)v1.x; o[5] = (f16)v1.y; o[6] = (f16)v1.z; o[7] = (f16)v1.w;
    }
    *(f16x8*)(cseq + ((size_t)row << 8) + lane * 8) = o;
}

// ---------------- weight pre-convert fp32 -> fp16 ----------------------------
// whalf layout: [ch=2i+d][sel: 0=Wi,1=Wh][row 768][k 256]
__global__ void k_prep_w(const float* __restrict__ Wi_f, const float* __restrict__ Wh_f,
                         const float* __restrict__ Wi_b, const float* __restrict__ Wh_b,
                         f16* __restrict__ whalf) {
    int ch2 = blockIdx.y;                // ch*2 + sel
    int ch = ch2 >> 1, sel = ch2 & 1;
    int i = ch >> 1, d = ch & 1;
    const float* src = sel ? (d ? Wh_b : Wh_f) : (d ? Wi_b : Wi_f);
    src += (size_t)i * 196608;
    int off = (blockIdx.x * 256 + threadIdx.x) * 4;
    float4 v = *(const float4*)(src + off);
    f16x4 o = { (f16)v.x, (f16)v.y, (f16)v.z, (f16)v.w };
    *(f16x4*)(whalf + (size_t)ch2 * 196608 + off) = o;
}

// W1 with LayerNorm gamma folded: w1g[i][n][c] = fp16(W1[i,n,c] * ln_g[i,c])
__global__ void k_prep_w1(const float* __restrict__ W1, const float* __restrict__ ln_g,
                          f16* __restrict__ w1g) {
    int off = (blockIdx.x * 256 + threadIdx.x) * 4;
    int i = off >> 17;           // / (256*512)
    int c = off & 511;
    float4 v = *(const float4*)(W1 + off);
    float4 g = *(const float4*)(ln_g + i * 512 + c);
    f16x4 o = { (f16)(v.x * g.x), (f16)(v.y * g.y), (f16)(v.z * g.z), (f16)(v.w * g.w) };
    *(f16x4*)(w1g + off) = o;
}

// wsum[i,n] = sum_c fp16(W1*g) ; c1[i,n] = sum_c W1*ln_b + b1
__global__ void k_prep_c(const float* __restrict__ W1, const float* __restrict__ ln_g,
                         const float* __restrict__ ln_b, const float* __restrict__ b1,
                         float* __restrict__ wsum, float* __restrict__ c1) {
    int row = blockIdx.x * 4 + (threadIdx.x >> 6);   // i*256 + n
    int lane = threadIdx.x & 63;
    int i = row >> 8;
    const float* src = W1 + (size_t)row * 512;
    float s1 = 0.f, s2 = 0.f;
#pragma unroll
    for (int e = 0; e < 8; e++) {
        int c = lane * 8 + e;
        float wv = src[c];
        s1 += (float)(f16)(wv * ln_g[i * 512 + c]);   // match GEMM's rounded weight
        s2 += wv * ln_b[i * 512 + c];
    }
#pragma unroll
    for (int off = 1; off < 64; off <<= 1) { s1 += __shfl_xor(s1, off); s2 += __shfl_xor(s2, off); }
    if (lane == 0) { wsum[row] = s1; c1[row] = s2 + b1[row]; }
}

// ---------------- zero-fill scores rows/halves never written by steps --------
__global__ void k_zfill(const int* __restrict__ scat_src, const int* __restrict__ seq_len,
                        f16* __restrict__ scores) {
    int j = blockIdx.x;
    int tid = threadIdx.x;
    int c = scat_src[j];
    if (c < 0) {                          // unmasked row: all 512 cols zero
        for (int i = 0; i < 8; i++) {
            unsigned int* p = (unsigned int*)(scores + ((size_t)(i * 16384 + j)) * 512);
            p[tid] = 0u;                  // 256 threads x 2 halfs = 512
        }
    } else {                              // masked row fed from past-end source: bwd half zero
        int st = c >> 10, sb = c & 1023;
        if (st >= seq_len[sb] && tid < 128) {
            for (int i = 0; i < 8; i++) {
                unsigned int* p = (unsigned int*)(scores + ((size_t)(i * 16384 + j)) * 512 + 256);
                p[tid] = 0u;
            }
        }
    }
}

// ---------------- persistent GRU: all 16 steps, h register/LDS-resident ------
// grid: 256 blocks (ch = bx&15 -> 2 chains per XCD, mseg = bx>>4, M=64 rows).
// 512 threads = 8 waves: rg = w>>2 (32-row group), ct = w&3 (16-col tile).
// Per step: prefetch x frags (regs); nt(4) x kt8(8): stage B (lds-direct,
// swizzled) -> 12 MFMA; epilogue: gates, h_reg update, scores scatter.
// h fp16 (A-layout, swizzled) committed to lH at step end.
__global__ __launch_bounds__(512, 2) void k_gru(
    const f16* __restrict__ cseq, const f16* __restrict__ whalf,
    const float* __restrict__ hx, f16* __restrict__ scores,
    const int* __restrict__ seq_len, const int* __restrict__ inv_scat,
    float* __restrict__ out)
{
    __shared__ f16 lH[64 * 256];   // 32 KB
    __shared__ f16 lB[192 * 64];   // 24 KB
    int bx = blockIdx.x;
    int ch = bx & 15, mseg = bx >> 4;
    int i = ch >> 1, d = ch & 1;
    int tid = threadIdx.x;
    int lane = tid & 63, w = tid >> 6;
    int li = lane & 15, q = lane >> 4;
    int rg = w >> 2, ct = w & 3;

    // preload seq_len
    int sl_frag[2], sl_epi[2][4];
#pragma unroll
    for (int s = 0; s < 2; s++) {
        sl_frag[s] = seq_len[mseg * 64 + rg * 32 + s * 16 + li];
#pragma unroll
        for (int r = 0; r < 4; r++)
            sl_epi[s][r] = seq_len[mseg * 64 + rg * 32 + s * 16 + q * 4 + r];
    }
    int T = seq_len[1024];

    // init h (fp32 regs, C-layout) + lH (fp16, A-layout, chunk^row swizzle)
    float h_reg[4][2][4];
#pragma unroll
    for (int nt = 0; nt < 4; nt++)
#pragma unroll
        for (int s = 0; s < 2; s++)
#pragma unroll
            for (int r = 0; r < 4; r++) {
                int row = rg * 32 + s * 16 + q * 4 + r;
                int c = nt * 64 + ct * 16 + li;
                float v = hx[((size_t)ch * 1024 + mseg * 64 + row) * 256 + c];
                h_reg[nt][s][r] = v;
                int chunk = c >> 3;
                int chs = (chunk & 24) | ((chunk ^ row) & 7);
                lH[row * 256 + chs * 8 + (c & 7)] = (f16)v;
            }

    // B staging slots (3 x 16B per thread per kt-chunk)
    const f16* wbase = whalf + (size_t)ch * 393216;
    int nrp[3], ckp[3];
#pragma unroll
    for (int p = 0; p < 3; p++) {
        int e = p * 512 + tid;
        nrp[p] = e >> 3;
        ckp[p] = (e & 7) ^ (nrp[p] & 7);   // swizzled source chunk
    }
    __syncthreads();

#pragma unroll 1
    for (int t = 0; t < 16; t++) {
        // x fragment prefetch: K=[0,256), both row-tiles, in regs
        f16x8 xf[4][2][2];   // [kt4][kk][s]
#pragma unroll
        for (int s = 0; s < 2; s++) {
            int b = mseg * 64 + rg * 32 + s * 16 + li;
            int tt = t;
            if (d) { tt = sl_frag[s] - 1 - t; if (tt < 0) tt = 0; } // clamp; masked later
            const f16* xrow = cseq + (((size_t)i * 16 + tt) * 1024 + b) * 256;
#pragma unroll
            for (int kt4 = 0; kt4 < 4; kt4++)
#pragma unroll
                for (int kk = 0; kk < 2; kk++)
                    xf[kt4][kk][s] = *(const f16x8*)(xrow + kt4 * 64 + kk * 32 + q * 8);
        }

#pragma unroll
        for (int nt = 0; nt < 4; nt++) {
            floatx4 ar_[2], az_[2], agi_[2], agh_[2];
            floatx4 z4 = {0.f, 0.f, 0.f, 0.f};
            ar_[0] = z4; ar_[1] = z4; az_[0] = z4; az_[1] = z4;
            agi_[0] = z4; agi_[1] = z4; agh_[0] = z4; agh_[1] = z4;
#pragma unroll
            for (int kt8 = 0; kt8 < 8; kt8++) {
                const int xph = (kt8 < 4);
                const int kofs = xph ? kt8 * 64 : (kt8 - 4) * 64;
                const f16* wsrc = wbase + (xph ? 0 : 196608);
#pragma unroll
                for (int p = 0; p < 3; p++) {
                    int nr = nrp[p];
                    int g = (nr >> 6) * 256 + nt * 64 + (nr & 63);
                    gl16(wsrc + (size_t)g * 256 + kofs + ckp[p] * 8, &lB[p * 4096 + w * 512]);
                }
                __syncthreads();
#pragma unroll
                for (int kk = 0; kk < 2; kk++) {
                    int bofs = ((kk * 4 + q) ^ (li & 7)) << 3;
                    f16x8 br = *(f16x8*)&lB[(ct * 16 + li) * 64 + bofs];
                    f16x8 bz = *(f16x8*)&lB[(64 + ct * 16 + li) * 64 + bofs];
                    f16x8 bn = *(f16x8*)&lB[(128 + ct * 16 + li) * 64 + bofs];
                    f16x8 a0, a1;
                    if (xph) {
                        a0 = xf[kt8][kk][0];
                        a1 = xf[kt8][kk][1];
                    } else {
                        int hofs = (((kt8 - 4) * 8) | ((kk * 4 + q) ^ (li & 7))) << 3;
                        a0 = *(f16x8*)&lH[(rg * 32 + li) * 256 + hofs];
                        a1 = *(f16x8*)&lH[(rg * 32 + 16 + li) * 256 + hofs];
                    }
                    ar_[0] = __builtin_amdgcn_mfma_f32_16x16x32_f16(a0, br, ar_[0], 0, 0, 0);
                    ar_[1] = __builtin_amdgcn_mfma_f32_16x16x32_f16(a1, br, ar_[1], 0, 0, 0);
                    az_[0] = __builtin_amdgcn_mfma_f32_16x16x32_f16(a0, bz, az_[0], 0, 0, 0);
                    az_[1] = __builtin_amdgcn_mfma_f32_16x16x32_f16(a1, bz, az_[1], 0, 0, 0);
                    if (xph) {
                        agi_[0] = __builtin_amdgcn_mfma_f32_16x16x32_f16(a0, bn, agi_[0], 0, 0, 0);
                        agi_[1] = __builtin_amdgcn_mfma_f32_16x16x32_f16(a1, bn, agi_[1], 0, 0, 0);
                    } else {
                        agh_[0] = __builtin_amdgcn_mfma_f32_16x16x32_f16(a0, bn, agh_[0], 0, 0, 0);
                        agh_[1] = __builtin_amdgcn_mfma_f32_16x16x32_f16(a1, bn, agh_[1], 0, 0, 0);
                    }
                }
                __syncthreads();
            }
            // epilogue nt: gates + h update (regs only) + scores scatter
#pragma unroll
            for (int s = 0; s < 2; s++) {
#pragma unroll
                for (int r = 0; r < 4; r++) {
                    int b = mseg * 64 + rg * 32 + s * 16 + q * 4 + r;
                    int sl = sl_epi[s][r];
                    int v = (t < sl);
                    int st = d ? (sl - 1 - t) : t;
                    int cfl = st * 1024 + b;
                    int j = -1;
                    if (d == 0) { if (cfl < T) j = inv_scat[cfl]; }
                    else        { if (v && cfl < T) j = inv_scat[cfl]; }
                    float rgt = sigf(ar_[s][r]);
                    float zgt = sigf(az_[s][r]);
                    float nn = tanhfast(agi_[s][r] + rgt * agh_[s][r]);
                    float hp = h_reg[nt][s][r];
                    float hn = (1.0f - zgt) * nn + zgt * hp;
                    h_reg[nt][s][r] = v ? hn : hp;
                    if (j >= 0) {
                        int c = nt * 64 + ct * 16 + li;
                        scores[((size_t)(i * 16384 + j)) * 512 + d * 256 + c] = (f16)(v ? hn : 0.0f);
                    }
                }
            }
        }
        // commit h to lH for next step (all lH reads finished at last kt8 sync)
#pragma unroll
        for (int nt = 0; nt < 4; nt++)
#pragma unroll
            for (int s = 0; s < 2; s++)
#pragma unroll
                for (int r = 0; r < 4; r++) {
                    int row = rg * 32 + s * 16 + q * 4 + r;
                    int c = nt * 64 + ct * 16 + li;
                    int chunk = c >> 3;
                    int chs = (chunk & 24) | ((chunk ^ row) & 7);
                    lH[row * 256 + chs * 8 + (c & 7)] = (f16)h_reg[nt][s][r];
                }
        __syncthreads();
    }

    // final hidden states -> coord_rnn_hxs (fp32), direct from regs
#pragma unroll
    for (int nt = 0; nt < 4; nt++)
#pragma unroll
        for (int s = 0; s < 2; s++)
#pragma unroll
            for (int r = 0; r < 4; r++) {
                int b = mseg * 64 + rg * 32 + s * 16 + q * 4 + r;
                int c = nt * 64 + ct * 16 + li;
                out[262144 + ((size_t)ch * 1024 + b) * 256 + c] = h_reg[nt][s][r];
            }
}

// ---------------- MLP with LN folded: rs*(s@Wg^T - mu*wsum) + c1 -------------
// grid: i(8) x mt(128, M=128); 512 threads. A/B both via lds-direct.
__global__ __launch_bounds__(512, 4) void k_mlp(
    const f16* __restrict__ scores, const f16* __restrict__ w1g,
    const float* __restrict__ wsum, const float* __restrict__ c1v,
    const float* __restrict__ W2, const float* __restrict__ b2,
    float* __restrict__ out)
{
    __shared__ f16 lA[128 * 64];          // 16 KB
    __shared__ f16 lB[256 * 64];          // 32 KB
    __shared__ float s_mu[128], s_rs[128];
    int bx = blockIdx.x;
    int i = bx >> 7, mt = bx & 127;
    int tid = threadIdx.x, lane = tid & 63, w = tid >> 6, li = lane & 15, q = lane >> 4;
    int rsub = lane >> 3;
    int sc = (lane & 7) ^ rsub;

    // stats pre-pass: 4 threads per row, 128 cols each (raw scores)
    {
        int r = tid >> 2, sub = tid & 3;
        const f16* sp = scores + ((size_t)(i * 16384 + mt * 128 + r)) * 512 + sub * 128;
        float s = 0.f, sq = 0.f;
#pragma unroll
        for (int e = 0; e < 16; e++) {
            uint4 raw = *(const uint4*)(sp + e * 8);
            f16x8 v = *(f16x8*)&raw;
#pragma unroll
            for (int u = 0; u < 8; u++) { float f = (float)v[u]; s += f; sq += f * f; }
        }
        s += __shfl_xor(s, 1); sq += __shfl_xor(sq, 1);
        s += __shfl_xor(s, 2); sq += __shfl_xor(sq, 2);
        if (sub == 0) {
            float mu = s * (1.0f / 512.0f);
            float var = sq * (1.0f / 512.0f) - mu * mu;
            if (var < 0.f) var = 0.f;
            s_mu[r] = mu;
            s_rs[r] = rsqrtf(var + 1e-5f);
        }
    }

    // staging source pointers
    const f16* pA[2]; const f16* pB[4];
#pragma unroll
    for (int p = 0; p < 2; p++) {
        int e = p * 512 + tid;
        int ar = e >> 3, chunk = e & 7;
        pA[p] = scores + ((size_t)(i * 16384 + mt * 128 + ar)) * 512 + ((chunk ^ (ar & 7)) * 8);
    }
#pragma unroll
    for (int p = 0; p < 4; p++) {
        int nr = (w * 4 + p) * 8 + rsub;                 // 0..255
        pB[p] = w1g + ((size_t)i * 256 + nr) * 512 + sc * 8;
    }

    floatx4 acc[16];
    floatx4 z4 = {0.f, 0.f, 0.f, 0.f};
#pragma unroll
    for (int n = 0; n < 16; n++) acc[n] = z4;
    __syncthreads();   // stats visible

    for (int kt = 0; kt < 512; kt += 64) {
#pragma unroll
        for (int p = 0; p < 2; p++) gl16(pA[p] + kt, &lA[p * 4096 + w * 512]);
#pragma unroll
        for (int p = 0; p < 4; p++) gl16(pB[p] + kt, &lB[(w * 4 + p) * 512]);
        __syncthreads();
#pragma unroll
        for (int kk = 0; kk < 64; kk += 32) {
            int sw = ((q + (kk >> 3)) ^ (li & 7)) << 3;
            f16x8 a = *(f16x8*)&lA[(w * 16 + li) * 64 + sw];
#pragma unroll
            for (int n = 0; n < 16; n++) {
                f16x8 bb = *(f16x8*)&lB[(n * 16 + li) * 64 + sw];
                acc[n] = __builtin_amdgcn_mfma_f32_16x16x32_f16(a, bb, acc[n], 0, 0, 0);
            }
        }
        __syncthreads();
    }

    // epilogue: h1 = rs*(acc - mu*wsum) + c1 ; relu ; W2 dot ; +b2
    float wsv[16], c1r[16], w2a[16], w2b[16];
#pragma unroll
    for (int n = 0; n < 16; n++) {
        int col = n * 16 + li;
        wsv[n] = wsum[i * 256 + col];
        c1r[n] = c1v[i * 256 + col];
        w2a[n] = W2[((size_t)i * 2 + 0) * 256 + col];
        w2b[n] = W2[((size_t)i * 2 + 1) * 256 + col];
    }
    float b2a = b2[i * 2], b2b = b2[i * 2 + 1];
#pragma unroll
    for (int r = 0; r < 4; r++) {
        int ml = w * 16 + q * 4 + r;
        float mu = s_mu[ml], rs = s_rs[ml];
        float p0 = 0.f, p1 = 0.f;
#pragma unroll
        for (int n = 0; n < 16; n++) {
            float h1 = rs * (acc[n][r] - mu * wsv[n]) + c1r[n];
            h1 = fmaxf(h1, 0.0f);
            p0 += h1 * w2a[n];
            p1 += h1 * w2b[n];
        }
#pragma unroll
        for (int off = 1; off < 16; off <<= 1) { p0 += __shfl_xor(p0, off); p1 += __shfl_xor(p1, off); }
        if (li == 0) {
            int m = mt * 128 + ml;
            size_t oi = ((size_t)i * 16384 + m) * 2;
            out[oi]     = p0 + b2a;
            out[oi + 1] = p1 + b2b;
        }
    }
}

// ---------------------------------------------------------------------------
extern "C" void kernel_launch(void* const* d_in, const int* in_sizes, int n_in,
                              void* d_out, int out_size, void* d_ws, size_t ws_size,
                              hipStream_t stream)
{
    const float* plans = (const float*)d_in[0];
    const float* comm  = (const float*)d_in[1];
    const float* hx    = (const float*)d_in[2];
    const float* dummy = (const float*)d_in[3];
    const float* Wi_f  = (const float*)d_in[4];
    const float* Wh_f  = (const float*)d_in[5];
    const float* Wi_b  = (const float*)d_in[6];
    const float* Wh_b  = (const float*)d_in[7];
    const float* ln_g  = (const float*)d_in[8];
    const float* ln_b  = (const float*)d_in[9];
    const float* W1    = (const float*)d_in[10];
    const float* b1    = (const float*)d_in[11];
    const float* W2    = (const float*)d_in[12];
    const float* b2    = (const float*)d_in[13];
    float* out = (float*)d_out;

    // ws layout, ~216.3 MB total
    char* ws = (char*)d_ws;
    f16*    cseq    = (f16*)   (ws + 0);            //  67,108,864 B
    f16*    scores  = (f16*)   (ws + 67108864);     // 134,217,728 B
    f16*    whalf   = (f16*)   (ws + 201326592);    //  12,582,912 B
    f16*    w1g     = (f16*)   (ws + 213909504);    //   2,097,152 B
    float*  wsum    = (float*) (ws + 216006656);    //       8,192 B
    float*  c1v     = (float*) (ws + 216014848);    //       8,192 B
    int*    empty   = (int*)   (ws + 216023040);    //       4,096 B
    int*    seq_len = (int*)   (ws + 216027136);    //       8,192 B (1025 used)
    int*    maskb   = (int*)   (ws + 216035328);    //      65,536 B
    int*    pack_s  = (int*)   (ws + 216100864);    //      65,536 B
    int*    scat_s  = (int*)   (ws + 216166400);    //      65,536 B
    int*    inv_s   = (int*)   (ws + 216231936);    //      65,536 B
    if (ws_size < 216297472ULL) return;  // fail readably instead of faulting

    k_empty<<<1024, 256, 0, stream>>>(comm, empty);
    k_mask<<<4096, 256, 0, stream>>>(plans, comm, empty, maskb);
    k_scan<<<1, 1024, 0, stream>>>(maskb, seq_len, pack_s, scat_s, inv_s);
    k_pack<<<16384, 256, 0, stream>>>(plans, comm, dummy, empty, pack_s, cseq);
    k_zfill<<<16384, 256, 0, stream>>>(scat_s, seq_len, scores);
    k_prep_w<<<dim3(192, 32), 256, 0, stream>>>(Wi_f, Wh_f, Wi_b, Wh_b, whalf);
    k_prep_w1<<<1024, 256, 0, stream>>>(W1, ln_g, w1g);
    k_prep_c<<<512, 256, 0, stream>>>(W1, ln_g, ln_b, b1, wsum, c1v);
    k_gru<<<256, 512, 0, stream>>>(cseq, whalf, hx, scores, seq_len, inv_s, out);
    k_mlp<<<1024, 512, 0, stream>>>(scores, w1g, wsum, c1v, W2, b2, out);
}

// Round 5
// 764.524 us; speedup vs baseline: 1.7471x; 1.7471x over previous
//
#include <hip/hip_runtime.h>

// ---------------------------------------------------------------------------
// Coordinator: 8 agents, bidirectional GRU over ragged-packed sequences.
// I/O fp32. Internal compute: fp16 MFMA (fp32 accumulate), h kept fp32.
// R5 = R3 structure (16 k_step launches, 512 blocks, wave-overlap friendly)
//      + XCD-pinned decode (ch = bx & 15): chain weights L2-resident per XCD,
//      warm across launches. Single-variable test of the weight-traffic theory.
// ---------------------------------------------------------------------------

typedef _Float16 f16;
typedef __attribute__((ext_vector_type(4))) _Float16 f16x4;
typedef __attribute__((ext_vector_type(8))) _Float16 f16x8;
typedef __attribute__((ext_vector_type(4))) float floatx4;

__device__ __forceinline__ float sigf(float x) { return 1.0f / (1.0f + __expf(-x)); }
__device__ __forceinline__ float tanhfast(float x) {
    float e = __expf(2.0f * x);
    return 1.0f - 2.0f / (e + 1.0f);   // saturates correctly, no NaN at +/-inf
}

// async global->LDS, 16B per lane; lds dst = wave-uniform base + lane*16
__device__ __forceinline__ void gl16(const f16* g, f16* l) {
    __builtin_amdgcn_global_load_lds((const __attribute__((address_space(1))) void*)g,
                                     (__attribute__((address_space(3))) void*)l,
                                     16, 0, 0);
}

// ---------------- empty[b] = no nonzero in comm_plans[b,:,:] -----------------
__global__ void k_empty(const float* __restrict__ comm, int* __restrict__ empty) {
    int b = blockIdx.x;
    __shared__ int flag;
    if (threadIdx.x == 0) flag = 0;
    __syncthreads();
    const float* p = comm + (size_t)b * 1024;   // 8*128
    int any = 0;
    for (int e = threadIdx.x; e < 1024; e += 256)
        if (p[e] != 0.0f) any = 1;              // -0.0 compares equal to 0
    if (any) flag = 1;
    __syncthreads();
    if (threadIdx.x == 0) empty[b] = (flag == 0);
}

// ---------------- mask[t*1024+b]: t>=8 -> 1 ; t<8 -> any(comm_sel != 0) ------
__global__ void k_mask(const float* __restrict__ plans, const float* __restrict__ comm,
                       const int* __restrict__ empty, int* __restrict__ mask) {
    int row = blockIdx.x * 4 + (threadIdx.x >> 6);   // one wave per (t,b) row
    int lane = threadIdx.x & 63;
    int t = row >> 10, b = row & 1023;
    int m;
    if (t >= 8) {
        m = 1;
    } else {
        const float* src = (empty[b] ? plans : comm) + ((size_t)b * 8 + t) * 128;
        float v0 = src[lane * 2], v1 = src[lane * 2 + 1];
        m = __any((v0 != 0.0f) || (v1 != 0.0f)) ? 1 : 0;
    }
    if (lane == 0) mask[row] = m;
}

// ---------------- single-block scan: seq_len, pack_src, scat_src, inv_scat ---
// Reproduces torch flat row-major boolean-index / masked_scatter semantics.
__global__ void k_scan(const int* __restrict__ mask, int* __restrict__ seq_len,
                       int* __restrict__ pack_src, int* __restrict__ scat_src,
                       int* __restrict__ inv_scat) {
    __shared__ int s_sl[1024];
    __shared__ int s_m[1024];
    __shared__ int s_p[1024];
    __shared__ unsigned short s_idx[16384];  // src_idx (j fits in 16 bits)
    int tid = threadIdx.x;
    int sl = 8;
    for (int t = 0; t < 8; t++) sl += mask[t * 1024 + tid];
    s_sl[tid] = sl;
    seq_len[tid] = sl;
    __syncthreads();
    int mv[16], pv[16];
    int mc = 0, pc = 0;
    int j0 = tid * 16;
    for (int q = 0; q < 16; q++) {
        int j = j0 + q;
        mv[q] = mask[j];
        pv[q] = ((j >> 10) < s_sl[j & 1023]) ? 1 : 0;
        mc += mv[q]; pc += pv[q];
    }
    s_m[tid] = mc; s_p[tid] = pc;
    __syncthreads();
    for (int off = 1; off < 1024; off <<= 1) {   // Hillis-Steele inclusive scan
        int am = (tid >= off) ? s_m[tid - off] : 0;
        int ap = (tid >= off) ? s_p[tid - off] : 0;
        __syncthreads();
        s_m[tid] += am; s_p[tid] += ap;
        __syncthreads();
    }
    if (tid == 1023) seq_len[1024] = s_m[1023];  // T = total masked count
    int moff = s_m[tid] - mc;    // exclusive prefixes
    int poff = s_p[tid] - pc;
    int rm = moff;
    for (int q = 0; q < 16; q++)
        if (mv[q]) s_idx[rm++] = (unsigned short)(j0 + q);
    __syncthreads();
    rm = moff;
    int rp = poff;
    for (int q = 0; q < 16; q++) {
        int j = j0 + q;
        scat_src[j] = mv[q] ? rm : -1;
        if (mv[q]) { inv_scat[rm] = j; rm++; }
        pack_src[j] = pv[q] ? (int)s_idx[rp] : -1;
        if (pv[q]) rp++;
    }
}

// ---------------- gather packed sequences: cseq[i][t][b][c] (fp16) -----------
// block = 8 rows x 32 lanes; lane covers 8 contiguous cols (2x float4 load).
__global__ void k_pack(const float* __restrict__ plans, const float* __restrict__ comm,
                       const float* __restrict__ dummy, const int* __restrict__ empty,
                       const int* __restrict__ pack_src, f16* __restrict__ cseq) {
    int row = blockIdx.x * 8 + (threadIdx.x >> 5);   // i*16384 + j
    int lane = threadIdx.x & 31;
    int i = row >> 14;
    int j = row & 16383;
    int s = pack_src[j];
    f16x8 o = {0, 0, 0, 0, 0, 0, 0, 0};
    if (s >= 0) {
        int tp = s >> 10, bp = s & 1023;
        const float* src;
        if (tp < 8) {
            if (lane < 16) src = plans + ((size_t)bp * 8 + i) * 128 + lane * 8;
            else src = (empty[bp] ? plans : comm) + ((size_t)bp * 8 + tp) * 128 + (lane - 16) * 8;
        } else {
            src = dummy + (((size_t)i * 8 + (tp - 8)) * 1024 + bp) * 256 + lane * 8;
        }
        float4 v0 = *(const float4*)src;
        float4 v1 = *(const float4*)(src + 4);
        o[0] = (f16)v0.x; o[1] = (f16)v0.y; o[2] = (f16)v0.z; o[3] = (f16)v0.w;
        o[4] = (f16)v1.x; o[5] = (f16)v1.y; o[6] = (f16)v1.z; o[7] = (f16)v1.w;
    }
    *(f16x8*)(cseq + ((size_t)row << 8) + lane * 8) = o;
}

// ---------------- weight pre-convert fp32 -> fp16 ----------------------------
// whalf layout: [ch=2i+d][sel: 0=Wi,1=Wh][row 768][k 256]
__global__ void k_prep_w(const float* __restrict__ Wi_f, const float* __restrict__ Wh_f,
                         const float* __restrict__ Wi_b, const float* __restrict__ Wh_b,
                         f16* __restrict__ whalf) {
    int ch2 = blockIdx.y;                // ch*2 + sel
    int ch = ch2 >> 1, sel = ch2 & 1;
    int i = ch >> 1, d = ch & 1;
    const float* src = sel ? (d ? Wh_b : Wh_f) : (d ? Wi_b : Wi_f);
    src += (size_t)i * 196608;
    int off = (blockIdx.x * 256 + threadIdx.x) * 4;
    float4 v = *(const float4*)(src + off);
    f16x4 o = { (f16)v.x, (f16)v.y, (f16)v.z, (f16)v.w };
    *(f16x4*)(whalf + (size_t)ch2 * 196608 + off) = o;
}

__global__ void k_prep_w1(const float* __restrict__ W1, f16* __restrict__ w1half) {
    int off = (blockIdx.x * 256 + threadIdx.x) * 4;
    float4 v = *(const float4*)(W1 + off);
    f16x4 o = { (f16)v.x, (f16)v.y, (f16)v.z, (f16)v.w };
    *(f16x4*)(w1half + off) = o;
}

// ---------------- init h (fp32 copy) + fp16 shadow ---------------------------
__global__ void k_init_h(const float* __restrict__ hx, float* __restrict__ h,
                         f16* __restrict__ hh0) {
    int e = (blockIdx.x * 256 + threadIdx.x) * 4;
    float4 v = *(const float4*)(hx + e);
    *(float4*)(h + e) = v;
    f16x4 o = { (f16)v.x, (f16)v.y, (f16)v.z, (f16)v.w };
    *(f16x4*)(hh0 + e) = o;
}

// ---------------- zero-fill scores rows/halves never written by steps --------
__global__ void k_zfill(const int* __restrict__ scat_src, const int* __restrict__ seq_len,
                        f16* __restrict__ scores) {
    int j = blockIdx.x;
    int tid = threadIdx.x;
    int c = scat_src[j];
    if (c < 0) {                          // unmasked row: all 512 cols zero
        for (int i = 0; i < 8; i++) {
            unsigned int* p = (unsigned int*)(scores + ((size_t)(i * 16384 + j)) * 512);
            p[tid] = 0u;                  // 256 threads x 2 halfs = 512
        }
    } else {                              // masked row fed from past-end source: bwd half zero
        int st = c >> 10, sb = c & 1023;
        if (st >= seq_len[sb] && tid < 128) {
            for (int i = 0; i < 8; i++) {
                unsigned int* p = (unsigned int*)(scores + ((size_t)(i * 16384 + j)) * 512 + 256);
                p[tid] = 0u;
            }
        }
    }
}

// ---------------- fused per-step GRU: GEMM + gates + h update + score write --
// grid 512: ch = bx&15 (XCD-pinned: chain ch -> XCD ch%8), mt=(bx>>4)&7, nt=bx>>7.
// LDS unpadded 64-half rows, chunk XOR (row&7) swizzle; staging via lds-direct.
__global__ __launch_bounds__(256, 2) void k_step(
    const f16* __restrict__ cseq, const f16* __restrict__ whalf,
    float* __restrict__ h, const f16* __restrict__ hh_in, f16* __restrict__ hh_out,
    f16* __restrict__ scores, const int* __restrict__ seq_len,
    const int* __restrict__ inv_scat, int t)
{
    __shared__ f16 lA[128 * 64];          // 16 KB
    __shared__ f16 lB[192 * 64];          // 24 KB
    int bx = blockIdx.x;
    int ch = bx & 15;                     // XCD-pinned chain
    int mt = (bx >> 4) & 7;
    int nt = bx >> 7;
    int i = ch >> 1, d = ch & 1;
    int tid = threadIdx.x;
    int lane = tid & 63, w = tid >> 6;
    int li = lane & 15, q = lane >> 4;
    int rsub = lane >> 3;                 // 0..7 (row within 8-row region)
    int sc = (lane & 7) ^ rsub;           // swizzled source chunk for this lane

    // per-lane staging source pointers (fixed across kt)
    const f16* pA[4]; const f16* pH[4]; const f16* pB[6];
#pragma unroll
    for (int p = 0; p < 4; p++) {
        int ar = (w * 4 + p) * 8 + rsub;
        int b = mt * 128 + ar;
        int tt = t;
        if (d) { int sl = seq_len[b]; tt = sl - 1 - t; if (tt < 0) tt = 0; } // clamp; masked later
        pA[p] = cseq + (((size_t)i * 16 + tt) * 1024 + b) * 256 + sc * 8;
        pH[p] = hh_in + ((size_t)ch * 1024 + b) * 256 + sc * 8;
    }
#pragma unroll
    for (int p = 0; p < 6; p++) {
        int nr = (w * 6 + p) * 8 + rsub;                 // 0..191
        int g = (nr >> 6) * 256 + nt * 64 + (nr & 63);   // gate-group row
        pB[p] = whalf + (size_t)(ch * 2) * 196608 + (size_t)g * 256 + sc * 8;
    }

    floatx4 accr[4][2], accz[4][2], accgi[4][2], accgh[4][2];
    floatx4 z4 = {0.f, 0.f, 0.f, 0.f};
#pragma unroll
    for (int n = 0; n < 4; n++)
        for (int s = 0; s < 2; s++) { accr[n][s] = z4; accz[n][s] = z4; accgi[n][s] = z4; accgh[n][s] = z4; }

    for (int kt = 0; kt < 512; kt += 64) {
        bool xph = (kt < 256);
        if (xph) {
#pragma unroll
            for (int p = 0; p < 4; p++) gl16(pA[p] + kt, &lA[(w * 4 + p) * 512]);
#pragma unroll
            for (int p = 0; p < 6; p++) gl16(pB[p] + kt, &lB[(w * 6 + p) * 512]);
        } else {
#pragma unroll
            for (int p = 0; p < 4; p++) gl16(pH[p] + (kt - 256), &lA[(w * 4 + p) * 512]);
#pragma unroll
            for (int p = 0; p < 6; p++) gl16(pB[p] + 196608 + (kt - 256), &lB[(w * 6 + p) * 512]);
        }
        __syncthreads();
#pragma unroll
        for (int kk = 0; kk < 64; kk += 32) {
            int sw = ((q + (kk >> 3)) ^ (li & 7)) << 3;   // swizzled chunk offset (halves)
            f16x8 a0 = *(f16x8*)&lA[(w * 32 + li) * 64 + sw];
            f16x8 a1 = *(f16x8*)&lA[(w * 32 + 16 + li) * 64 + sw];
#pragma unroll
            for (int n = 0; n < 4; n++) {
                f16x8 br = *(f16x8*)&lB[(n * 16 + li) * 64 + sw];
                f16x8 bz = *(f16x8*)&lB[(64 + n * 16 + li) * 64 + sw];
                f16x8 bn = *(f16x8*)&lB[(128 + n * 16 + li) * 64 + sw];
                accr[n][0] = __builtin_amdgcn_mfma_f32_16x16x32_f16(a0, br, accr[n][0], 0, 0, 0);
                accr[n][1] = __builtin_amdgcn_mfma_f32_16x16x32_f16(a1, br, accr[n][1], 0, 0, 0);
                accz[n][0] = __builtin_amdgcn_mfma_f32_16x16x32_f16(a0, bz, accz[n][0], 0, 0, 0);
                accz[n][1] = __builtin_amdgcn_mfma_f32_16x16x32_f16(a1, bz, accz[n][1], 0, 0, 0);
                if (xph) {
                    accgi[n][0] = __builtin_amdgcn_mfma_f32_16x16x32_f16(a0, bn, accgi[n][0], 0, 0, 0);
                    accgi[n][1] = __builtin_amdgcn_mfma_f32_16x16x32_f16(a1, bn, accgi[n][1], 0, 0, 0);
                } else {
                    accgh[n][0] = __builtin_amdgcn_mfma_f32_16x16x32_f16(a0, bn, accgh[n][0], 0, 0, 0);
                    accgh[n][1] = __builtin_amdgcn_mfma_f32_16x16x32_f16(a1, bn, accgh[n][1], 0, 0, 0);
                }
            }
        }
        __syncthreads();
    }

    // epilogue: gates + h update + direct masked_scatter score write
    int T = seq_len[1024];
#pragma unroll
    for (int s = 0; s < 2; s++) {
#pragma unroll
        for (int r = 0; r < 4; r++) {
            int b = mt * 128 + w * 32 + s * 16 + q * 4 + r;
            int sl = seq_len[b];
            int v = (t < sl);
            int st = d ? (sl - 1 - t) : t;
            int cfl = st * 1024 + b;
            int j = -1;
            if (d == 0) { if (cfl < T) j = inv_scat[cfl]; }
            else        { if (v && cfl < T) j = inv_scat[cfl]; }
#pragma unroll
            for (int n = 0; n < 4; n++) {
                int c = nt * 64 + n * 16 + li;
                float rg = sigf(accr[n][s][r]);
                float zg = sigf(accz[n][s][r]);
                float nn = tanhfast(accgi[n][s][r] + rg * accgh[n][s][r]);
                size_t hidx = ((size_t)ch * 1024 + b) * 256 + c;
                float hp = h[hidx];
                float hn = (1.0f - zg) * nn + zg * hp;
                float hnew = v ? hn : hp;
                h[hidx] = hnew;
                hh_out[hidx] = (f16)hnew;
                if (j >= 0)
                    scores[((size_t)(i * 16384 + j)) * 512 + d * 256 + c] = (f16)(v ? hn : 0.0f);
            }
        }
    }
}

// ---------------- fused LN(stats+apply) + MLP -> coord_masks -----------------
// grid: i(8) x mt(128, M=128); 512 threads (8 waves). N=256, K=512.
__global__ __launch_bounds__(512, 4) void k_mlp(
    const f16* __restrict__ scores,
    const float* __restrict__ ln_g, const float* __restrict__ ln_b,
    const f16* __restrict__ w1half, const float* __restrict__ b1,
    const float* __restrict__ W2, const float* __restrict__ b2,
    float* __restrict__ out)
{
    __shared__ f16 lA[128 * 64];          // 16 KB
    __shared__ f16 lB[256 * 64];          // 32 KB
    __shared__ float s_mu[128], s_rs[128];
    int bx = blockIdx.x;
    int i = bx >> 7, mt = bx & 127;
    int tid = threadIdx.x, lane = tid & 63, w = tid >> 6, li = lane & 15, q = lane >> 4;
    int rsub = lane >> 3;
    int sc = (lane & 7) ^ rsub;

    // ---- stats pre-pass: 4 threads per row, 128 cols each ----
    {
        int r = tid >> 2, sub = tid & 3;
        const f16* sp = scores + ((size_t)(i * 16384 + mt * 128 + r)) * 512 + sub * 128;
        float s = 0.f, sq = 0.f;
#pragma unroll
        for (int e = 0; e < 16; e++) {
            uint4 raw = *(const uint4*)(sp + e * 8);
            f16x8 v = *(f16x8*)&raw;
#pragma unroll
            for (int u = 0; u < 8; u++) { float f = (float)v[u]; s += f; sq += f * f; }
        }
        s += __shfl_xor(s, 1); sq += __shfl_xor(sq, 1);
        s += __shfl_xor(s, 2); sq += __shfl_xor(sq, 2);
        if (sub == 0) {
            float mu = s * (1.0f / 512.0f);
            float var = sq * (1.0f / 512.0f) - mu * mu;
            if (var < 0.f) var = 0.f;
            s_mu[r] = mu;
            s_rs[r] = rsqrtf(var + 1e-5f);
        }
    }

    // B source pointers (lds-direct)
    const f16* pB[4];
#pragma unroll
    for (int p = 0; p < 4; p++) {
        int nr = (w * 4 + p) * 8 + rsub;                 // 0..255
        pB[p] = w1half + ((size_t)i * 256 + nr) * 512 + sc * 8;
    }

    floatx4 acc[16];
    floatx4 z4 = {0.f, 0.f, 0.f, 0.f};
#pragma unroll
    for (int n = 0; n < 16; n++) acc[n] = z4;
    __syncthreads();   // stats visible

    for (int kt = 0; kt < 512; kt += 64) {
        // A stage (manual, LN applied on load, swizzled store)
#pragma unroll
        for (int p = 0; p < 2; p++) {
            int e = p * 512 + tid;
            int ar = e >> 3, chk = e & 7;
            int m = mt * 128 + ar;
            uint4 raw = *(const uint4*)(scores + ((size_t)(i * 16384 + m)) * 512 + kt + chk * 8);
            f16x8 sv = *(f16x8*)&raw;
            float mu = s_mu[ar], rs = s_rs[ar];
            int co = i * 512 + kt + chk * 8;
            float4 g0 = *(const float4*)(ln_g + co);
            float4 g1 = *(const float4*)(ln_g + co + 4);
            float4 t0 = *(const float4*)(ln_b + co);
            float4 t1 = *(const float4*)(ln_b + co + 4);
            f16x8 ov;
            ov[0] = (f16)(((float)sv[0] - mu) * rs * g0.x + t0.x);
            ov[1] = (f16)(((float)sv[1] - mu) * rs * g0.y + t0.y);
            ov[2] = (f16)(((float)sv[2] - mu) * rs * g0.z + t0.z);
            ov[3] = (f16)(((float)sv[3] - mu) * rs * g0.w + t0.w);
            ov[4] = (f16)(((float)sv[4] - mu) * rs * g1.x + t1.x);
            ov[5] = (f16)(((float)sv[5] - mu) * rs * g1.y + t1.y);
            ov[6] = (f16)(((float)sv[6] - mu) * rs * g1.z + t1.z);
            ov[7] = (f16)(((float)sv[7] - mu) * rs * g1.w + t1.w);
            *(f16x8*)&lA[ar * 64 + ((chk ^ (ar & 7)) << 3)] = ov;
        }
        // B stage: lds-direct
#pragma unroll
        for (int p = 0; p < 4; p++) gl16(pB[p] + kt, &lB[(w * 4 + p) * 512]);
        __syncthreads();
#pragma unroll
        for (int kk = 0; kk < 64; kk += 32) {
            int sw = ((q + (kk >> 3)) ^ (li & 7)) << 3;
            f16x8 a = *(f16x8*)&lA[(w * 16 + li) * 64 + sw];
#pragma unroll
            for (int n = 0; n < 16; n++) {
                f16x8 bb = *(f16x8*)&lB[(n * 16 + li) * 64 + sw];
                acc[n] = __builtin_amdgcn_mfma_f32_16x16x32_f16(a, bb, acc[n], 0, 0, 0);
            }
        }
        __syncthreads();
    }

    // epilogue: relu + W2 dot, reduce over 16 lanes of the quad-row
    float b1v[16], w2a[16], w2b[16];
#pragma unroll
    for (int n = 0; n < 16; n++) {
        int col = n * 16 + li;
        b1v[n] = b1[i * 256 + col];
        w2a[n] = W2[((size_t)i * 2 + 0) * 256 + col];
        w2b[n] = W2[((size_t)i * 2 + 1) * 256 + col];
    }
    float b2a = b2[i * 2], b2b = b2[i * 2 + 1];
#pragma unroll
    for (int r = 0; r < 4; r++) {
        float p0 = 0.f, p1 = 0.f;
#pragma unroll
        for (int n = 0; n < 16; n++) {
            float h1 = acc[n][r] + b1v[n];
            h1 = fmaxf(h1, 0.0f);
            p0 += h1 * w2a[n];
            p1 += h1 * w2b[n];
        }
#pragma unroll
        for (int off = 1; off < 16; off <<= 1) { p0 += __shfl_xor(p0, off); p1 += __shfl_xor(p1, off); }
        if (li == 0) {
            int m = mt * 128 + w * 16 + q * 4 + r;
            size_t oi = ((size_t)i * 16384 + m) * 2;
            out[oi]     = p0 + b2a;
            out[oi + 1] = p1 + b2b;
        }
    }
}

// ---------------- final hidden states -> coord_rnn_hxs (fp32) ----------------
__global__ void k_hout(const float* __restrict__ h, float* __restrict__ out) {
    int e = (blockIdx.x * 256 + threadIdx.x) * 4;
    *(float4*)(out + 262144 + e) = *(const float4*)(h + e);
}

// ---------------------------------------------------------------------------
extern "C" void kernel_launch(void* const* d_in, const int* in_sizes, int n_in,
                              void* d_out, int out_size, void* d_ws, size_t ws_size,
                              hipStream_t stream)
{
    const float* plans = (const float*)d_in[0];
    const float* comm  = (const float*)d_in[1];
    const float* hx    = (const float*)d_in[2];
    const float* dummy = (const float*)d_in[3];
    const float* Wi_f  = (const float*)d_in[4];
    const float* Wh_f  = (const float*)d_in[5];
    const float* Wi_b  = (const float*)d_in[6];
    const float* Wh_b  = (const float*)d_in[7];
    const float* ln_g  = (const float*)d_in[8];
    const float* ln_b  = (const float*)d_in[9];
    const float* W1    = (const float*)d_in[10];
    const float* b1    = (const float*)d_in[11];
    const float* W2    = (const float*)d_in[12];
    const float* b2    = (const float*)d_in[13];
    float* out = (float*)d_out;

    // ws layout, ~251 MB total
    char* ws = (char*)d_ws;
    f16*    cseq    = (f16*)   (ws + 0);            //  67,108,864 B
    f16*    scores  = (f16*)   (ws + 67108864);     // 134,217,728 B
    float*  h       = (float*) (ws + 201326592);    //  16,777,216 B
    f16*    hh0     = (f16*)   (ws + 218103808);    //   8,388,608 B
    f16*    hh1     = (f16*)   (ws + 226492416);    //   8,388,608 B
    f16*    whalf   = (f16*)   (ws + 234881024);    //  12,582,912 B
    f16*    w1half  = (f16*)   (ws + 247463936);    //   2,097,152 B
    int*    empty   = (int*)   (ws + 250609664);    //       4,096 B
    int*    seq_len = (int*)   (ws + 250613760);    //       8,192 B (1025 used)
    int*    maskb   = (int*)   (ws + 250621952);    //      65,536 B
    int*    pack_s  = (int*)   (ws + 250687488);    //      65,536 B
    int*    scat_s  = (int*)   (ws + 250753024);    //      65,536 B
    int*    inv_s   = (int*)   (ws + 250818560);    //      65,536 B
    if (ws_size < 250884096ULL) return;  // fail readably instead of faulting

    k_empty<<<1024, 256, 0, stream>>>(comm, empty);
    k_mask<<<4096, 256, 0, stream>>>(plans, comm, empty, maskb);
    k_scan<<<1, 1024, 0, stream>>>(maskb, seq_len, pack_s, scat_s, inv_s);
    k_pack<<<16384, 256, 0, stream>>>(plans, comm, dummy, empty, pack_s, cseq);
    k_zfill<<<16384, 256, 0, stream>>>(scat_s, seq_len, scores);
    k_prep_w<<<dim3(192, 32), 256, 0, stream>>>(Wi_f, Wh_f, Wi_b, Wh_b, whalf);
    k_prep_w1<<<1024, 256, 0, stream>>>(W1, w1half);
    k_init_h<<<4096, 256, 0, stream>>>(hx, h, hh0);
    for (int t = 0; t < 16; t++) {
        f16* hin  = (t & 1) ? hh1 : hh0;
        f16* hout = (t & 1) ? hh0 : hh1;
        k_step<<<512, 256, 0, stream>>>(cseq, whalf, h, hin, hout, scores,
                                        seq_len, inv_s, t);
    }
    k_mlp<<<1024, 512, 0, stream>>>(scores, ln_g, ln_b, w1half, b1, W2, b2, out);
    k_hout<<<4096, 256, 0, stream>>>(h, out);
}